// Round 1
// baseline (69.800 us; speedup 1.0000x reference)
//
#include <hip/hip_runtime.h>
#include <math.h>

// LFQ: D=20 bits, K=2^20, TEMP=0.005, x:[2,128,20] fp32, 256 tokens.
// Factorized softmax over the +-1 hypercube codebook:
//   p_t(k) = prod_j sigma(2 x_tj / T)^(b_kj) * sigma(-2 x_tj / T)^(1-b_kj)
// entropy_t = sum_j H(sigma(400 x_tj)); mean_probs M = (1/256) Hi^T Lo
// (10/10 bit split); mean_entro = -sum_k M_k log(M_k + 1e-10).
//
// R8: single-kernel. R7's counter profile shows the measured time is
// dominated by the harness's 256 MiB workspace poison fill (39.3 us at
// 85% HBM peak — untouchable) plus our dispatch structure. All four
// output scalars are LINEAR in per-block partials, so the finish kernel
// is replaced by 4 device-scope float atomicAdds per block into
// out[5120..5123], zero-initialized by a 16 B hipMemsetAsync node
// (graph-capturable; re-poison safe since it re-zeroes every replay).
// The workspace and the second kernel dispatch are gone entirely.

#define RS 264    // panel row stride in ushorts: 528B rows; frag reads and
                  // column writes both bank-phase conflict-free

typedef float f32x4 __attribute__((ext_vector_type(4)));
typedef short bf16x8 __attribute__((ext_vector_type(8)));

__device__ inline unsigned short pk_bf16(float a) {  // RNE f32->bf16
  unsigned ua = __float_as_uint(a);
  ua += 0x7FFFu + ((ua >> 16) & 1u);
  return (unsigned short)(ua >> 16);
}

__global__ __launch_bounds__(512) void lfq_main(
    const float* __restrict__ x, float* __restrict__ out) {
  const int blk = blockIdx.x;
  const int tid = threadIdx.x;
  const int lane = tid & 63, w = tid >> 6;

  __shared__ unsigned short sP[128 * RS];   // A rows 0..63, B rows 64..127
  __shared__ float wpart[8];

  // ---- phase 1: this block's token scalars (wave 0 only, shuffle-reduced)
  // h / cterm survive in tid 0's registers until the final atomics.
  float h = 0.f, cterm = 0.f;
  if (tid < 64) {
    if (tid < 20) {
      float xv = x[blk * 20 + tid];
      float z = 400.f * xv, az = fabsf(z);
      float e = __expf(-az), s = e / (1.f + e);
      h = log1pf(e) + az * s;               // stable binary entropy (nats)
      float qv = (xv > 0.f) ? 1.f : -1.f;
      out[blk * 20 + tid] = qv;             // straight-through forward value
      float dx = xv - qv;
      cterm = dx * dx;
    }
#pragma unroll
    for (int off = 32; off > 0; off >>= 1) {
      h += __shfl_down(h, off, 64);
      cterm += __shfl_down(cterm, off, 64);
    }
  }

  // ---- phase 2: build this side's panel column t, all in registers ----
  {
    const int side = tid >> 8;               // 0: A-panel, 1: B-panel
    const int t = tid & 255;
    const int jo = side * 10;                // x-column offset for this side
    const int hi4 = side ? (blk >> 4) : (blk & 15);  // tile's fixed 4 bits

    float p[10];
    const float2* xp = (const float2*)(x + t * 20 + jo);
#pragma unroll
    for (int k = 0; k < 5; ++k) {
      float2 v = xp[k];
      float zz0 = 400.f * v.x, zz1 = 400.f * v.y;
      float a0 = fabsf(zz0), a1 = fabsf(zz1);
      float e0 = __expf(-a0), e1 = __expf(-a1);
      float s0 = e0 / (1.f + e0), s1 = e1 / (1.f + e1);
      p[2 * k]     = (zz0 >= 0.f) ? (1.f - s0) : s0;
      p[2 * k + 1] = (zz1 >= 0.f) ? (1.f - s1) : s1;
    }
    float c = 1.f;
#pragma unroll
    for (int j = 0; j < 4; ++j)
      c *= ((hi4 >> (3 - j)) & 1) ? p[j] : (1.f - p[j]);
    float cvh[8], vl[8];
#pragma unroll
    for (int g = 0; g < 8; ++g) {
      cvh[g] = c * ((g & 4) ? p[4] : 1.f - p[4])
                 * ((g & 2) ? p[5] : 1.f - p[5])
                 * ((g & 1) ? p[6] : 1.f - p[6]);
      vl[g]  =     ((g & 4) ? p[7] : 1.f - p[7])
                 * ((g & 2) ? p[8] : 1.f - p[8])
                 * ((g & 1) ? p[9] : 1.f - p[9]);
    }
    unsigned short* panel = sP + side * 64 * RS;
#pragma unroll
    for (int r = 0; r < 64; ++r)
      panel[r * RS + t] = pk_bf16(cvh[r >> 3] * vl[r & 7]);
  }
  __syncthreads();

  // ---- phase 3: tile GEMM. wave w: rows (w&3)*16, cols (w>>2)*32 ----
  // A-frag lane: A[m=lane&15][k=q*8+j]; B-frag lane: B[k][n=lane&15];
  // both t-contiguous 16B reads. C/D layout irrelevant (pure reduction).
  const int m16 = lane & 15, q = lane >> 4;
  const unsigned short* ap = sP + ((w & 3) * 16 + m16) * RS + q * 8;
  const unsigned short* bp = sP + (64 + (w >> 2) * 32 + m16) * RS + q * 8;
  f32x4 acc0 = {0.f, 0.f, 0.f, 0.f}, acc1 = {0.f, 0.f, 0.f, 0.f};
#pragma unroll
  for (int ks = 0; ks < 8; ++ks) {
    bf16x8 af = *(const bf16x8*)(ap + ks * 32);
    bf16x8 b0 = *(const bf16x8*)(bp + ks * 32);
    bf16x8 b1 = *(const bf16x8*)(bp + 16 * RS + ks * 32);
    acc0 = __builtin_amdgcn_mfma_f32_16x16x32_bf16(af, b0, acc0, 0, 0, 0);
    acc1 = __builtin_amdgcn_mfma_f32_16x16x32_bf16(af, b1, acc1, 0, 0, 0);
  }

  // ---- phase 4: -m*log(m+1e-10) epilogue, shuffle reduce ----
  float ts = 0.f;
#pragma unroll
  for (int i = 0; i < 4; ++i) {
    float m0 = acc0[i] * (1.f / 256.f);
    ts -= m0 * __logf(m0 + 1e-10f);
    float m1 = acc1[i] * (1.f / 256.f);
    ts -= m1 * __logf(m1 + 1e-10f);
  }
#pragma unroll
  for (int off = 32; off > 0; off >>= 1) ts += __shfl_down(ts, off, 64);
  if (lane == 0) wpart[w] = ts;
  __syncthreads();

  // ---- phase 5: fold this block's partials straight into the outputs ----
  // All four scalars are linear in per-block partials; device-scope float
  // atomicAdd is XCD-coherent with no fence. 256 adds/address: trivial
  // contention. out[5120..5123] zeroed by the memset node in kernel_launch.
  if (tid == 0) {
    float s = 0.f;
#pragma unroll
    for (int i = 0; i < 8; ++i) s += wpart[i];
    float e256 = h * (1.f / 256.f);          // this token's entro_mean share
    atomicAdd(out + 5120, e256);             // entro_mean_s
    atomicAdd(out + 5121, s);                // mean_entro
    atomicAdd(out + 5122, e256 - s);         // entro_loss (ALPHA=1)
    atomicAdd(out + 5123, cterm * (1.f / 5120.f));  // commit_loss
  }
}

extern "C" void kernel_launch(void* const* d_in, const int* in_sizes, int n_in,
                              void* d_out, int out_size, void* d_ws, size_t ws_size,
                              hipStream_t stream) {
  const float* x = (const float*)d_in[0];
  float* out = (float*)d_out;
  (void)d_ws; (void)ws_size;

  // Zero the 4 scalar accumulators (16 B). Graph-capturable fill node;
  // re-zeroes on every replay, so atomics are re-poison safe.
  hipMemsetAsync((char*)d_out + 5120 * sizeof(float), 0, 4 * sizeof(float),
                 stream);
  lfq_main<<<256, 512, 0, stream>>>(x, out);
}

// Round 2
// 57.656 us; speedup vs baseline: 1.2106x; 1.2106x over previous
//
#include <hip/hip_runtime.h>
#include <math.h>

// LFQ: D=20 bits, K=2^20, TEMP=0.005, x:[2,128,20] fp32, 256 tokens.
// Factorized softmax over the +-1 hypercube codebook:
//   p_t(k) = prod_j sigma(2 x_tj / T)^(b_kj) * sigma(-2 x_tj / T)^(1-b_kj)
// entropy_t = sum_j H(sigma(400 x_tj)); mean_probs M = (1/256) Hi^T Lo
// (10/10 bit split); mean_entro = -sum_k M_k log(M_k + 1e-10).
//
// R9: revert to R7 (harness-verified 57.2 us). R8 post-mortem: replacing
// the finish kernel with 4 same-cache-line device-scope atomicAdds per
// block serialized ~1024 RMWs at the coherence point (+12.6 us), and the
// 16 B hipMemsetAsync became a fillBufferAligned kernel dispatch anyway
// (no node savings). Fence-free two-kernel structure restored: kernel 1
// ends with three plain float stores per block (no fence, no atomic);
// a trivial 1-block kernel 2 reduces 3x256 partials and writes the 4
// scalars. Cross-kernel visibility is the kernel-boundary release/acquire
// (one CP-managed L2 writeback total, not 256).

#define RS 264    // panel row stride in ushorts: 528B rows; frag reads and
                  // column writes both bank-phase conflict-free

typedef float f32x4 __attribute__((ext_vector_type(4)));
typedef short bf16x8 __attribute__((ext_vector_type(8)));

__device__ inline unsigned short pk_bf16(float a) {  // RNE f32->bf16
  unsigned ua = __float_as_uint(a);
  ua += 0x7FFFu + ((ua >> 16) & 1u);
  return (unsigned short)(ua >> 16);
}

__global__ __launch_bounds__(512) void lfq_main(
    const float* __restrict__ x, float* __restrict__ out,
    float* __restrict__ entP, float* __restrict__ comP,
    float* __restrict__ meP) {
  const int blk = blockIdx.x;
  const int tid = threadIdx.x;
  const int lane = tid & 63, w = tid >> 6;

  __shared__ unsigned short sP[128 * RS];   // A rows 0..63, B rows 64..127
  __shared__ float wpart[8];

  // ---- phase 1: this block's token scalars (wave 0 only, shuffle-reduced)
  if (tid < 64) {
    float h = 0.f, cterm = 0.f;
    if (tid < 20) {
      float xv = x[blk * 20 + tid];
      float z = 400.f * xv, az = fabsf(z);
      float e = __expf(-az), s = e / (1.f + e);
      h = log1pf(e) + az * s;               // stable binary entropy (nats)
      float qv = (xv > 0.f) ? 1.f : -1.f;
      out[blk * 20 + tid] = qv;             // straight-through forward value
      float dx = xv - qv;
      cterm = dx * dx;
    }
#pragma unroll
    for (int off = 32; off > 0; off >>= 1) {
      h += __shfl_down(h, off, 64);
      cterm += __shfl_down(cterm, off, 64);
    }
    if (tid == 0) { entP[blk] = h; comP[blk] = cterm; }  // plain stores
  }

  // ---- phase 2: build this side's panel column t, all in registers ----
  {
    const int side = tid >> 8;               // 0: A-panel, 1: B-panel
    const int t = tid & 255;
    const int jo = side * 10;                // x-column offset for this side
    const int hi4 = side ? (blk >> 4) : (blk & 15);  // tile's fixed 4 bits

    float p[10];
    const float2* xp = (const float2*)(x + t * 20 + jo);
#pragma unroll
    for (int k = 0; k < 5; ++k) {
      float2 v = xp[k];
      float zz0 = 400.f * v.x, zz1 = 400.f * v.y;
      float a0 = fabsf(zz0), a1 = fabsf(zz1);
      float e0 = __expf(-a0), e1 = __expf(-a1);
      float s0 = e0 / (1.f + e0), s1 = e1 / (1.f + e1);
      p[2 * k]     = (zz0 >= 0.f) ? (1.f - s0) : s0;
      p[2 * k + 1] = (zz1 >= 0.f) ? (1.f - s1) : s1;
    }
    float c = 1.f;
#pragma unroll
    for (int j = 0; j < 4; ++j)
      c *= ((hi4 >> (3 - j)) & 1) ? p[j] : (1.f - p[j]);
    float cvh[8], vl[8];
#pragma unroll
    for (int g = 0; g < 8; ++g) {
      cvh[g] = c * ((g & 4) ? p[4] : 1.f - p[4])
                 * ((g & 2) ? p[5] : 1.f - p[5])
                 * ((g & 1) ? p[6] : 1.f - p[6]);
      vl[g]  =     ((g & 4) ? p[7] : 1.f - p[7])
                 * ((g & 2) ? p[8] : 1.f - p[8])
                 * ((g & 1) ? p[9] : 1.f - p[9]);
    }
    unsigned short* panel = sP + side * 64 * RS;
#pragma unroll
    for (int r = 0; r < 64; ++r)
      panel[r * RS + t] = pk_bf16(cvh[r >> 3] * vl[r & 7]);
  }
  __syncthreads();

  // ---- phase 3: tile GEMM. wave w: rows (w&3)*16, cols (w>>2)*32 ----
  // A-frag lane: A[m=lane&15][k=q*8+j]; B-frag lane: B[k][n=lane&15];
  // both t-contiguous 16B reads. C/D layout irrelevant (pure reduction).
  const int m16 = lane & 15, q = lane >> 4;
  const unsigned short* ap = sP + ((w & 3) * 16 + m16) * RS + q * 8;
  const unsigned short* bp = sP + (64 + (w >> 2) * 32 + m16) * RS + q * 8;
  f32x4 acc0 = {0.f, 0.f, 0.f, 0.f}, acc1 = {0.f, 0.f, 0.f, 0.f};
#pragma unroll
  for (int ks = 0; ks < 8; ++ks) {
    bf16x8 af = *(const bf16x8*)(ap + ks * 32);
    bf16x8 b0 = *(const bf16x8*)(bp + ks * 32);
    bf16x8 b1 = *(const bf16x8*)(bp + 16 * RS + ks * 32);
    acc0 = __builtin_amdgcn_mfma_f32_16x16x32_bf16(af, b0, acc0, 0, 0, 0);
    acc1 = __builtin_amdgcn_mfma_f32_16x16x32_bf16(af, b1, acc1, 0, 0, 0);
  }

  // ---- phase 4: -m*log(m+1e-10) epilogue, shuffle reduce, plain store ----
  float ts = 0.f;
#pragma unroll
  for (int i = 0; i < 4; ++i) {
    float m0 = acc0[i] * (1.f / 256.f);
    ts -= m0 * __logf(m0 + 1e-10f);
    float m1 = acc1[i] * (1.f / 256.f);
    ts -= m1 * __logf(m1 + 1e-10f);
  }
#pragma unroll
  for (int off = 32; off > 0; off >>= 1) ts += __shfl_down(ts, off, 64);
  if (lane == 0) wpart[w] = ts;
  __syncthreads();
  if (tid == 0) {
    float s = 0.f;
#pragma unroll
    for (int i = 0; i < 8; ++i) s += wpart[i];
    meP[blk] = s;                            // plain store; kernel boundary
  }                                          // publishes it to kernel 2
}

__global__ __launch_bounds__(256) void lfq_finish(
    const float* __restrict__ entP, const float* __restrict__ comP,
    const float* __restrict__ meP, float* __restrict__ out) {
  const int tid = threadIdx.x;
  const int lane = tid & 63, w = tid >> 6;
  __shared__ float fe[4], fc[4], fm[4];
  float e = entP[tid], cs = comP[tid], m = meP[tid];
#pragma unroll
  for (int off = 32; off > 0; off >>= 1) {
    e  += __shfl_down(e, off, 64);
    cs += __shfl_down(cs, off, 64);
    m  += __shfl_down(m, off, 64);
  }
  if (lane == 0) { fe[w] = e; fc[w] = cs; fm[w] = m; }
  __syncthreads();
  if (tid == 0) {
    float E = 0.f, C = 0.f, M = 0.f;
#pragma unroll
    for (int i = 0; i < 4; ++i) { E += fe[i]; C += fc[i]; M += fm[i]; }
    double em = (double)E / 256.0;           // entro_mean_s
    double cm = (double)C / 5120.0;          // commit_loss
    double me = (double)M;                   // mean_entro
    out[5120] = (float)em;
    out[5121] = (float)me;
    out[5122] = (float)(em - me);            // entro_loss (ALPHA=1)
    out[5123] = (float)cm;
  }
}

extern "C" void kernel_launch(void* const* d_in, const int* in_sizes, int n_in,
                              void* d_out, int out_size, void* d_ws, size_t ws_size,
                              hipStream_t stream) {
  const float* x = (const float*)d_in[0];
  float* out = (float*)d_out;
  char* ws = (char*)d_ws;
  float* entP = (float*)(ws);                 // 256 floats
  float* comP = (float*)(ws + 1024);          // 256 floats
  float* meP  = (float*)(ws + 2048);          // 256 floats

  lfq_main<<<256, 512, 0, stream>>>(x, out, entP, comP, meP);
  lfq_finish<<<1, 256, 0, stream>>>(entP, comP, meP, out);
}